// Round 1
// baseline (1019.627 us; speedup 1.0000x reference)
//
#include <hip/hip_runtime.h>

// Problem constants (fixed by the reference setup).
#define BATCH 256
#define SEQT  2048
#define LAYERS 4
#define HID   64
// P (input / projected hidden size) == 1

__device__ __forceinline__ float fast_rcp(float x) {
    return __builtin_amdgcn_rcpf(x);
}

// sigmoid(x) = 1 / (1 + e^-x); v_exp + v_rcp, ~1 ulp each, saturates correctly.
__device__ __forceinline__ float fast_sigmoid(float x) {
    return fast_rcp(1.0f + __expf(-x));
}

// tanh(x) = 1 - 2/(e^{2x} + 1); correct limits at +-inf.
__device__ __forceinline__ float fast_tanh(float x) {
    return fmaf(-2.0f, fast_rcp(__expf(2.0f * x) + 1.0f), 1.0f);
}

// One block per batch element. 4 waves = 4 layers (software pipeline across
// time: wave l at barrier-iteration it processes t = it - l). Lane k = hidden
// unit k. h (scalar per batch per layer) passed between waves via
// double-buffered LDS; c lives per-lane in registers.
__global__ __launch_bounds__(256, 1) void lstm_pipeline_kernel(
    const float* __restrict__ y,      // [B, T, 1]
    const float* __restrict__ W_ih,   // [L, 4H, 1]
    const float* __restrict__ W_hh,   // [L, 4H, 1]
    const float* __restrict__ b_ih,   // [L, 4H]
    const float* __restrict__ b_hh,   // [L, 4H]
    const float* __restrict__ W_hr,   // [L, 1, H]
    const int*  __restrict__ msl_p,   // min_seq_len scalar
    float* __restrict__ out)          // [B, T - msl, 1]
{
    const int b   = blockIdx.x;
    const int tid = threadIdx.x;
    const int l   = tid >> 6;   // layer / wave id
    const int k   = tid & 63;   // hidden unit / lane
    const int msl = *msl_p;

    __shared__ float y_lds[SEQT];          // staged input row (8 KB)
    __shared__ float h_pipe[2][LAYERS];    // double-buffered inter-layer h

    // Stage y[b, :] into LDS with float4 loads (2 per thread).
    {
        const float4* y4  = (const float4*)(y + (size_t)b * SEQT);
        float4*       yl4 = (float4*)y_lds;
        #pragma unroll
        for (int i = tid; i < SEQT / 4; i += 256) yl4[i] = y4[i];
    }

    // Loop-invariant weights for this (layer, hidden unit). Gate order: i,f,g,o.
    const int wbase = l * 4 * HID;
    const float wi0 = W_ih[wbase + 0 * HID + k];
    const float wi1 = W_ih[wbase + 1 * HID + k];
    const float wi2 = W_ih[wbase + 2 * HID + k];
    const float wi3 = W_ih[wbase + 3 * HID + k];
    const float wh0 = W_hh[wbase + 0 * HID + k];
    const float wh1 = W_hh[wbase + 1 * HID + k];
    const float wh2 = W_hh[wbase + 2 * HID + k];
    const float wh3 = W_hh[wbase + 3 * HID + k];
    const float bb0 = b_ih[wbase + 0 * HID + k] + b_hh[wbase + 0 * HID + k];
    const float bb1 = b_ih[wbase + 1 * HID + k] + b_hh[wbase + 1 * HID + k];
    const float bb2 = b_ih[wbase + 2 * HID + k] + b_hh[wbase + 2 * HID + k];
    const float bb3 = b_ih[wbase + 3 * HID + k] + b_hh[wbase + 3 * HID + k];
    const float wr  = W_hr[l * HID + k];

    float h = 0.0f;   // projected hidden (wave-uniform after reduce)
    float c = 0.0f;   // cell state, per lane

    float* outb = out + (size_t)b * (SEQT - msl);

    // Pipelined time loop: T + L - 1 barrier-iterations.
    for (int it = 0; it < SEQT + LAYERS - 1; ++it) {
        __syncthreads();   // makes previous iteration's h_pipe writes visible
        const int t = it - l;
        if (t >= 0 && t < SEQT) {
            // Input scalar: layer 0 from LDS-staged y, others from the pipe.
            const float x = (l == 0) ? y_lds[t] : h_pipe[(it - 1) & 1][l - 1];

            float gi = fmaf(h, wh0, fmaf(x, wi0, bb0));
            float gf = fmaf(h, wh1, fmaf(x, wi1, bb1));
            float gg = fmaf(h, wh2, fmaf(x, wi2, bb2));
            float go = fmaf(h, wh3, fmaf(x, wi3, bb3));

            const float si = fast_sigmoid(gi);
            const float sf = fast_sigmoid(gf);
            const float tg = fast_tanh(gg);
            const float so = fast_sigmoid(go);

            c = fmaf(sf, c, si * tg);

            float v = so * fast_tanh(c) * wr;

            // 64-lane xor-butterfly: every lane ends with the full sum.
            #pragma unroll
            for (int m = 32; m >= 1; m >>= 1) v += __shfl_xor(v, m, 64);
            h = v;

            if (k == 0) {
                if (l < LAYERS - 1) {
                    h_pipe[it & 1][l] = h;       // feed next layer (read next iter)
                } else if (t >= msl) {
                    outb[t - msl] = h;            // final layer output
                }
            }
        }
    }
}

extern "C" void kernel_launch(void* const* d_in, const int* in_sizes, int n_in,
                              void* d_out, int out_size, void* d_ws, size_t ws_size,
                              hipStream_t stream) {
    const float* y    = (const float*)d_in[0];
    const float* W_ih = (const float*)d_in[1];
    const float* W_hh = (const float*)d_in[2];
    const float* b_ih = (const float*)d_in[3];
    const float* b_hh = (const float*)d_in[4];
    const float* W_hr = (const float*)d_in[5];
    const int*   msl  = (const int*)d_in[6];
    float* out = (float*)d_out;

    lstm_pipeline_kernel<<<BATCH, 256, 0, stream>>>(
        y, W_ih, W_hh, b_ih, b_hh, W_hr, msl, out);
}

// Round 2
// 489.119 us; speedup vs baseline: 2.0846x; 2.0846x over previous
//
#include <hip/hip_runtime.h>

// Problem constants (fixed by the reference setup).
#define BATCH  256
#define SEQT   2048
#define LAYERS 4
#define HID    64
#define CHUNK  8                         // timesteps per barrier phase
#define PHASES (SEQT / CHUNK + LAYERS - 1)
// P (input / projected hidden size) == 1

__device__ __forceinline__ float fast_rcp(float x) {
    return __builtin_amdgcn_rcpf(x);
}

// sigmoid(x) = 1 / (1 + e^-x); v_exp + v_rcp, saturates correctly at +-inf.
__device__ __forceinline__ float fast_sigmoid(float x) {
    return fast_rcp(1.0f + __expf(-x));
}

// tanh(x) = 1 - 2/(e^{2x} + 1); correct limits at +-inf.
__device__ __forceinline__ float fast_tanh(float x) {
    return fmaf(-2.0f, fast_rcp(__expf(2.0f * x) + 1.0f), 1.0f);
}

// One DPP-shifted add: v += dpp_move(v). bound_ctrl=true -> invalid lanes read 0.
#define DPP_ADD(v, ctrl)                                                     \
    (v) += __int_as_float(__builtin_amdgcn_update_dpp(                       \
        0, __float_as_int(v), (ctrl), 0xF, 0xF, true))

// Full wave64 sum via DPP prefix + row broadcasts; result lands in lane 63,
// then readlane broadcasts it as a wave-uniform (SGPR) value.
// row_shr:N = 0x110|N, row_bcast15 = 0x142, row_bcast31 = 0x143.
__device__ __forceinline__ float wave_sum_uniform(float v) {
    DPP_ADD(v, 0x111);   // += lane-1   (within 16-lane row, 0-fill)
    DPP_ADD(v, 0x112);   // += lane-2
    DPP_ADD(v, 0x114);   // += lane-4
    DPP_ADD(v, 0x118);   // += lane-8   -> lane 15/31/47/63 = row sums
    DPP_ADD(v, 0x142);   // row_bcast15 -> lane63 += row2 sum (lane47)
    DPP_ADD(v, 0x143);   // row_bcast31 -> lane63 += row0+row1 (lane31)
    return __int_as_float(__builtin_amdgcn_readlane(__float_as_int(v), 63));
}

// One block per batch element. 4 waves = 4 layers, software-pipelined across
// time in CHUNK-step phases: wave l in phase p handles t in [C*(p-l), +C).
// Inter-layer h values flow through double-buffered LDS once per phase.
// Lane k = hidden unit k; c per-lane in registers; h wave-uniform (SGPR).
__global__ __launch_bounds__(256, 1) void lstm_pipeline_kernel(
    const float* __restrict__ y,      // [B, T, 1]
    const float* __restrict__ W_ih,   // [L, 4H, 1]
    const float* __restrict__ W_hh,   // [L, 4H, 1]
    const float* __restrict__ b_ih,   // [L, 4H]
    const float* __restrict__ b_hh,   // [L, 4H]
    const float* __restrict__ W_hr,   // [L, 1, H]
    const int*  __restrict__ msl_p,   // min_seq_len scalar
    float* __restrict__ out)          // [B, T - msl, 1]
{
    const int b   = blockIdx.x;
    const int tid = threadIdx.x;
    const int l   = tid >> 6;   // layer / wave id
    const int k   = tid & 63;   // hidden unit / lane
    const int msl = *msl_p;

    __shared__ float y_lds[SEQT];                              // 8 KB
    __shared__ __align__(16) float h_buf[2][LAYERS][CHUNK];    // inter-layer h

    // Stage y[b, :] into LDS with float4 loads.
    {
        const float4* y4  = (const float4*)(y + (size_t)b * SEQT);
        float4*       yl4 = (float4*)y_lds;
        #pragma unroll
        for (int i = tid; i < SEQT / 4; i += 256) yl4[i] = y4[i];
    }

    // Loop-invariant weights for this (layer, hidden unit). Gate order: i,f,g,o.
    const int wbase = l * 4 * HID;
    const float wi0 = W_ih[wbase + 0 * HID + k];
    const float wi1 = W_ih[wbase + 1 * HID + k];
    const float wi2 = W_ih[wbase + 2 * HID + k];
    const float wi3 = W_ih[wbase + 3 * HID + k];
    const float wh0 = W_hh[wbase + 0 * HID + k];
    const float wh1 = W_hh[wbase + 1 * HID + k];
    const float wh2 = W_hh[wbase + 2 * HID + k];
    const float wh3 = W_hh[wbase + 3 * HID + k];
    const float bb0 = b_ih[wbase + 0 * HID + k] + b_hh[wbase + 0 * HID + k];
    const float bb1 = b_ih[wbase + 1 * HID + k] + b_hh[wbase + 1 * HID + k];
    const float bb2 = b_ih[wbase + 2 * HID + k] + b_hh[wbase + 2 * HID + k];
    const float bb3 = b_ih[wbase + 3 * HID + k] + b_hh[wbase + 3 * HID + k];
    const float wr  = W_hr[l * HID + k];

    float h = 0.0f;   // projected hidden (wave-uniform)
    float c = 0.0f;   // cell state, per lane

    float* outb = out + (size_t)b * (SEQT - msl);

    for (int p = 0; p < PHASES; ++p) {
        __syncthreads();   // publishes previous phase's h_buf writes
        const int t0 = (p - l) * CHUNK;
        if (t0 >= 0 && t0 < SEQT) {
            // Fetch this chunk's 8 scalar inputs (wave-uniform broadcast reads).
            float4 xa, xb;
            if (l == 0) {
                xa = *(const float4*)&y_lds[t0];
                xb = *(const float4*)&y_lds[t0 + 4];
            } else {
                const float4* hb = (const float4*)&h_buf[(p - 1) & 1][l - 1][0];
                xa = hb[0];
                xb = hb[1];
            }
            const float xs[CHUNK] = {xa.x, xa.y, xa.z, xa.w,
                                     xb.x, xb.y, xb.z, xb.w};

            // Input-side gate contributions: independent of h, off the chain.
            float p0[CHUNK], p1[CHUNK], p2[CHUNK], p3[CHUNK];
            #pragma unroll
            for (int j = 0; j < CHUNK; ++j) {
                p0[j] = fmaf(xs[j], wi0, bb0);
                p1[j] = fmaf(xs[j], wi1, bb1);
                p2[j] = fmaf(xs[j], wi2, bb2);
                p3[j] = fmaf(xs[j], wi3, bb3);
            }

            #pragma unroll
            for (int j = 0; j < CHUNK; ++j) {
                const float gi = fmaf(h, wh0, p0[j]);
                const float gf = fmaf(h, wh1, p1[j]);
                const float gg = fmaf(h, wh2, p2[j]);
                const float go = fmaf(h, wh3, p3[j]);

                const float si = fast_sigmoid(gi);
                const float sf = fast_sigmoid(gf);
                const float tg = fast_tanh(gg);
                const float so = fast_sigmoid(go);

                c = fmaf(sf, c, si * tg);

                const float sw = so * wr;          // ready before tanh(c)
                const float v  = fast_tanh(c) * sw;

                h = wave_sum_uniform(v);           // ~6 VALU ops + readlane

                if (l < LAYERS - 1) {
                    if (k == 0) h_buf[p & 1][l][j] = h;   // feed next layer
                } else {
                    const int t = t0 + j;
                    if (t >= msl && k == 0) outb[t - msl] = h;
                }
            }
        }
    }
}

extern "C" void kernel_launch(void* const* d_in, const int* in_sizes, int n_in,
                              void* d_out, int out_size, void* d_ws, size_t ws_size,
                              hipStream_t stream) {
    const float* y    = (const float*)d_in[0];
    const float* W_ih = (const float*)d_in[1];
    const float* W_hh = (const float*)d_in[2];
    const float* b_ih = (const float*)d_in[3];
    const float* b_hh = (const float*)d_in[4];
    const float* W_hr = (const float*)d_in[5];
    const int*   msl  = (const int*)d_in[6];
    float* out = (float*)d_out;

    lstm_pipeline_kernel<<<BATCH, 256, 0, stream>>>(
        y, W_ih, W_hh, b_ih, b_hh, W_hr, msl, out);
}